// Round 1
// baseline (339.862 us; speedup 1.0000x reference)
//
#include <hip/hip_runtime.h>

typedef __attribute__((ext_vector_type(4))) float f32x4;
typedef __attribute__((ext_vector_type(8))) short bf16x8;
typedef __attribute__((ext_vector_type(4))) unsigned short u16x4;
typedef unsigned short u16;
typedef unsigned int u32;

// B=4 T=4096 C=1024 H=16 LS=256
#define M_  16384   // B*T
#define C_  1024
#define N1_ 3072    // 3C

__device__ __forceinline__ float bf2f(u16 u) {
  union { u32 i; float f; } v; v.i = ((u32)u) << 16; return v.f;
}
__device__ __forceinline__ u16 f2bf(float f) {
  union { float f; u32 i; } v; v.f = f;
  u32 r = v.i + 0x7fffu + ((v.i >> 16) & 1u);   // RN-even
  return (u16)(r >> 16);
}

__device__ __forceinline__ void gload16(const void* g, void* l) {
  __builtin_amdgcn_global_load_lds(
      (const __attribute__((address_space(1))) u32*)g,
      (__attribute__((address_space(3))) u32*)l, 16, 0, 0);
}

// ---------------- casts ----------------
__global__ __launch_bounds__(256) void cast_f32_bf16(const float* __restrict__ in,
                                                     u16* __restrict__ out) {
  size_t i = (size_t)blockIdx.x * 256 + threadIdx.x;
  typedef __attribute__((ext_vector_type(4))) float f4v;
  f4v v = ((const f4v*)in)[i];
  u16x4 o = { f2bf(v[0]), f2bf(v[1]), f2bf(v[2]), f2bf(v[3]) };
  ((u16x4*)out)[i] = o;
}

// in[K][N] fp32 -> out[N][K] bf16   (N % 256 == 0)
__global__ __launch_bounds__(256) void transpose_cast(const float* __restrict__ in,
                                                      u16* __restrict__ out, int K, int N) {
  int n = blockIdx.x * 256 + threadIdx.x;
  int k = blockIdx.y;
  out[(size_t)n * K + k] = f2bf(in[(size_t)k * N + n]);
}

// ---------------- GEMM: C[M][N] = A[M][K] * BT[N][K]^T, bf16 in, fp32 acc ----------------
__device__ __forceinline__ void storeC(float* C, size_t i, float v) { C[i] = v; }
__device__ __forceinline__ void storeC(u16* C, size_t i, float v)   { C[i] = f2bf(v); }

template <typename OUT>
__global__ __launch_bounds__(256, 2) void gemm_bt(const u16* __restrict__ A,
                                                  const u16* __restrict__ BT,
                                                  OUT* __restrict__ C,
                                                  int M, int N, int K, int ntn) {
  __shared__ __align__(16) u16 smA[128 * 32];
  __shared__ __align__(16) u16 smB[128 * 32];
  const int bid = blockIdx.x;
  const int tm = (bid / ntn) * 128;
  const int tn = (bid % ntn) * 128;
  const int tid = threadIdx.x;
  const int lane = tid & 63;
  const int w = tid >> 6;
  const int wr = w >> 1, wc = w & 1;   // wave computes 64x64 at (wr*64, wc*64)

  f32x4 acc[4][4];
#pragma unroll
  for (int i = 0; i < 4; ++i)
#pragma unroll
    for (int j = 0; j < 4; ++j) acc[i][j] = (f32x4){0.f, 0.f, 0.f, 0.f};

  // staging: wave w loads rows [w*16, w*16+16) and +64 of each tile; lane: row +lane/4, 16B chunk lane%4
  const u16* gA = A + (size_t)(tm + w * 16 + (lane >> 2)) * K + (lane & 3) * 8;
  const u16* gB = BT + (size_t)(tn + w * 16 + (lane >> 2)) * K + (lane & 3) * 8;
  u16* sA0 = &smA[(w * 16) * 32];
  u16* sA1 = &smA[(w * 16 + 64) * 32];
  u16* sB0 = &smB[(w * 16) * 32];
  u16* sB1 = &smB[(w * 16 + 64) * 32];

  for (int k0 = 0; k0 < K; k0 += 32) {
    gload16(gA + k0, sA0);
    gload16(gA + (size_t)64 * K + k0, sA1);
    gload16(gB + k0, sB0);
    gload16(gB + (size_t)64 * K + k0, sB1);
    __syncthreads();
    bf16x8 af[4], bf[4];
#pragma unroll
    for (int i = 0; i < 4; ++i) {
      af[i] = *(const bf16x8*)&smA[(wr * 64 + i * 16 + (lane & 15)) * 32 + (lane >> 4) * 8];
      bf[i] = *(const bf16x8*)&smB[(wc * 64 + i * 16 + (lane & 15)) * 32 + (lane >> 4) * 8];
    }
#pragma unroll
    for (int mi = 0; mi < 4; ++mi)
#pragma unroll
      for (int ni = 0; ni < 4; ++ni)
        acc[mi][ni] = __builtin_amdgcn_mfma_f32_16x16x32_bf16(af[mi], bf[ni], acc[mi][ni], 0, 0, 0);
    __syncthreads();
  }

  // C/D layout: col = lane&15, row = (lane>>4)*4 + reg  [m89-verified]
  const int r0 = tm + wr * 64 + (lane >> 4) * 4;
  const int c0 = tn + wc * 64 + (lane & 15);
#pragma unroll
  for (int mi = 0; mi < 4; ++mi)
#pragma unroll
    for (int r = 0; r < 4; ++r) {
      size_t base = (size_t)(r0 + mi * 16 + r) * N + c0;
#pragma unroll
      for (int ni = 0; ni < 4; ++ni) storeC(C, base + ni * 16, acc[mi][ni][r]);
    }
}

// ---------------- RMSNorm of q,k parts of qkv (in place, bf16) ----------------
__global__ __launch_bounds__(256) void rmsnorm_qk(u16* __restrict__ qkv,
                                                  const float* __restrict__ lnw) {
  const size_t t = blockIdx.x;
  u16* row = qkv + t * N1_;
  const int tid = threadIdx.x;
  __shared__ float red[4];
#pragma unroll
  for (int part = 0; part < 2; ++part) {
    u16* p = row + part * C_;
    u16x4 v = ((const u16x4*)p)[tid];
    float f0 = bf2f(v[0]), f1 = bf2f(v[1]), f2 = bf2f(v[2]), f3 = bf2f(v[3]);
    float ss = f0 * f0 + f1 * f1 + f2 * f2 + f3 * f3;
#pragma unroll
    for (int o = 1; o < 64; o <<= 1) ss += __shfl_xor(ss, o, 64);
    if ((tid & 63) == 0) red[tid >> 6] = ss;
    __syncthreads();
    float sc = rsqrtf((red[0] + red[1] + red[2] + red[3]) * (1.0f / 1024.0f) + 1e-6f);
    const int c = tid * 4;
    u16x4 o4 = { f2bf(f0 * sc * lnw[c]), f2bf(f1 * sc * lnw[c + 1]),
                 f2bf(f2 * sc * lnw[c + 2]), f2bf(f3 * sc * lnw[c + 3]) };
    ((u16x4*)p)[tid] = o4;
    __syncthreads();
  }
}

// ---------------- block-causal attention ----------------
// grid: (b*16+g)*16 + h ; 256 threads (4 waves). LS=256, hd=64, scale=1/8.
// Swapped QK^T: mfma(A=K, B=Q) -> lane owns q-row (lane&15), k-local (lane>>4)*4+reg.
__global__ __launch_bounds__(256, 1) void attn_kernel(const u16* __restrict__ qkv,
                                                      u16* __restrict__ y) {
  const int bid = blockIdx.x;
  const int h = bid & 15;
  const int bg = bid >> 4;
  const size_t rowbase = (size_t)bg * 256;
  const u16* Qg = qkv + rowbase * N1_ + h * 64;
  const u16* Kg = Qg + C_;
  const u16* Vg = Qg + 2 * C_;

  __shared__ __align__(16) u16 Ks[256 * 64];       // [k_tok][hd], XOR-swizzled
  __shared__ __align__(16) u16 Vt[64 * 256];       // [hd][k_tok], XOR-swizzled
  __shared__ __align__(16) u16 Ps[4][16 * 256];    // per-wave P [q][k], XOR-swizzled

  const int tid = threadIdx.x;
  const int lane = tid & 63;
  const int w = tid >> 6;
  const int g = lane >> 4;
  const int qi = lane & 15;

  // load K,V: one token row per thread
  {
    const int r = tid;
    const u16* kr = Kg + (size_t)r * N1_;
    const u16* vr = Vg + (size_t)r * N1_;
    char* ksb = (char*)Ks + r * 128;
    const int swk = (r & 7) << 4;
#pragma unroll
    for (int j = 0; j < 8; ++j) {
      bf16x8 kv = *(const bf16x8*)(kr + j * 8);
      *(bf16x8*)(ksb + ((j * 16) ^ swk)) = kv;
      bf16x8 vv = *(const bf16x8*)(vr + j * 8);
#pragma unroll
      for (int e = 0; e < 8; ++e) {
        int d = j * 8 + e;
        *(u16*)((char*)Vt + d * 512 + ((2 * r) ^ ((d & 7) << 4))) = (u16)vv[e];
      }
    }
  }
  __syncthreads();

  const float scale = 0.125f;
  char* pb = (char*)Ps[w];
  const int swq = (qi & 7) << 4;

#pragma unroll 1
  for (int qt = w; qt < 16; qt += 4) {
    // Q B-frags straight from global: lane holds Q[qt*16+qi][g*8 .. +8], and +32
    const u16* qrow = Qg + (size_t)(qt * 16 + qi) * N1_ + g * 8;
    bf16x8 q0 = *(const bf16x8*)(qrow);
    bf16x8 q1 = *(const bf16x8*)(qrow + 32);

    f32x4 s[16];
#pragma unroll
    for (int n = 0; n < 16; ++n) {
      if (n <= qt) {
        const char* kb = (const char*)Ks + (n * 16 + qi) * 128;  // (row&7)==qi&7
        bf16x8 ka0 = *(const bf16x8*)(kb + ((g * 16) ^ swq));
        bf16x8 ka1 = *(const bf16x8*)(kb + ((g * 16 + 64) ^ swq));
        f32x4 a = {0.f, 0.f, 0.f, 0.f};
        a = __builtin_amdgcn_mfma_f32_16x16x32_bf16(ka0, q0, a, 0, 0, 0);
        a = __builtin_amdgcn_mfma_f32_16x16x32_bf16(ka1, q1, a, 0, 0, 0);
        s[n] = a;
      }
    }

    const int q_abs = qt * 16 + qi;
    float m = -3e38f;
#pragma unroll
    for (int n = 0; n < 16; ++n) if (n <= qt) {
#pragma unroll
      for (int r = 0; r < 4; ++r) {
        const int k_abs = n * 16 + g * 4 + r;
        float v = s[n][r] * scale;
        v = (k_abs <= q_abs) ? v : -3e38f;
        s[n][r] = v;
        m = fmaxf(m, v);
      }
    }
    m = fmaxf(m, __shfl_xor(m, 16, 64));
    m = fmaxf(m, __shfl_xor(m, 32, 64));

    float sum = 0.f;
#pragma unroll
    for (int n = 0; n < 16; ++n) if (n <= qt) {
#pragma unroll
      for (int r = 0; r < 4; ++r) {
        float p = __expf(s[n][r] - m);
        s[n][r] = p;
        sum += p;
      }
    }
    sum += __shfl_xor(sum, 16, 64);
    sum += __shfl_xor(sum, 32, 64);

    // P -> LDS (bf16, packed 4-k quads), swizzled
#pragma unroll
    for (int n = 0; n < 16; ++n) if (n <= qt) {
      u16x4 pk = { f2bf(s[n][0]), f2bf(s[n][1]), f2bf(s[n][2]), f2bf(s[n][3]) };
      *(u16x4*)(pb + qi * 512 + ((n * 32 + g * 8) ^ swq)) = pk;
    }
    if (!(qt & 1)) {   // zero-pad k-tile qt+1 (read by the last 32-wide mfma)
      u16x4 z = {0, 0, 0, 0};
      *(u16x4*)(pb + qi * 512 + (((qt + 1) * 32 + g * 8) ^ swq)) = z;
    }

    // PV: D = P * V
    f32x4 yacc[4];
#pragma unroll
    for (int dn = 0; dn < 4; ++dn) yacc[dn] = (f32x4){0.f, 0.f, 0.f, 0.f};
    const int nkf = qt / 2 + 1;
#pragma unroll
    for (int kf = 0; kf < 8; ++kf) if (kf < nkf) {
      bf16x8 pa = *(const bf16x8*)(pb + qi * 512 + ((kf * 64 + g * 16) ^ swq));
#pragma unroll
      for (int dn = 0; dn < 4; ++dn) {
        const int d = dn * 16 + qi;   // d&7 == qi&7
        bf16x8 vb = *(const bf16x8*)((const char*)Vt + d * 512 + ((kf * 64 + g * 16) ^ swq));
        yacc[dn] = __builtin_amdgcn_mfma_f32_16x16x32_bf16(pa, vb, yacc[dn], 0, 0, 0);
      }
    }

    // write y: row = (lane>>4)*4+reg (q-local), col = dn*16 + qi (d-local)
#pragma unroll
    for (int r = 0; r < 4; ++r) {
      const float inv = 1.0f / __shfl(sum, g * 4 + r, 64);
      const size_t trow = rowbase + (size_t)qt * 16 + g * 4 + r;
      u16* yrow = y + trow * C_ + h * 64 + qi;
#pragma unroll
      for (int dn = 0; dn < 4; ++dn) yrow[dn * 16] = f2bf(yacc[dn][r] * inv);
    }
  }
}

// ---------------- launch ----------------
extern "C" void kernel_launch(void* const* d_in, const int* in_sizes, int n_in,
                              void* d_out, int out_size, void* d_ws, size_t ws_size,
                              hipStream_t stream) {
  const float* x      = (const float*)d_in[0];   // [16384][1024]
  const float* w_qkv  = (const float*)d_in[1];   // [1024][3072]
  const float* ln_w   = (const float*)d_in[2];   // [1024]
  const float* w_proj = (const float*)d_in[3];   // [1024][1024]
  float* out = (float*)d_out;                    // [16384][1024] fp32

  u16* xb     = (u16*)d_ws;                          // 16384*1024
  u16* wqkvT  = xb + (size_t)M_ * C_;                // 3072*1024 (transposed)
  u16* wprojT = wqkvT + (size_t)N1_ * C_;            // 1024*1024 (transposed)
  u16* qkvb   = wprojT + (size_t)C_ * C_;            // 16384*3072
  u16* yb     = qkvb + (size_t)M_ * N1_;             // 16384*1024

  cast_f32_bf16<<<(M_ * C_) / 1024, 256, 0, stream>>>(x, xb);
  transpose_cast<<<dim3(N1_ / 256, C_), 256, 0, stream>>>(w_qkv, wqkvT, C_, N1_);
  transpose_cast<<<dim3(C_ / 256, C_), 256, 0, stream>>>(w_proj, wprojT, C_, C_);

  gemm_bt<u16><<<(M_ / 128) * (N1_ / 128), 256, 0, stream>>>(xb, wqkvT, qkvb, M_, N1_, C_, N1_ / 128);
  rmsnorm_qk<<<M_, 256, 0, stream>>>(qkvb, ln_w);
  attn_kernel<<<64 * 16, 256, 0, stream>>>(qkvb, yb);
  gemm_bt<float><<<(M_ / 128) * (C_ / 128), 256, 0, stream>>>(yb, wprojT, out, M_, C_, C_, C_ / 128);
}

// Round 2
// 329.573 us; speedup vs baseline: 1.0312x; 1.0312x over previous
//
#include <hip/hip_runtime.h>

typedef __attribute__((ext_vector_type(4))) float f32x4;
typedef __attribute__((ext_vector_type(8))) short bf16x8;
typedef __attribute__((ext_vector_type(4))) unsigned short u16x4;
typedef unsigned short u16;
typedef unsigned int u32;

// B=4 T=4096 C=1024 H=16 LS=256
#define M_  16384   // B*T
#define C_  1024
#define N1_ 3072    // 3C

__device__ __forceinline__ float bf2f(u16 u) {
  union { u32 i; float f; } v; v.i = ((u32)u) << 16; return v.f;
}
__device__ __forceinline__ u16 f2bf(float f) {
  union { float f; u32 i; } v; v.f = f;
  u32 r = v.i + 0x7fffu + ((v.i >> 16) & 1u);   // RN-even
  return (u16)(r >> 16);
}

__device__ __forceinline__ void gload16(const void* g, void* l) {
  __builtin_amdgcn_global_load_lds(
      (const __attribute__((address_space(1))) u32*)g,
      (__attribute__((address_space(3))) u32*)l, 16, 0, 0);
}

// ---------------- casts ----------------
__global__ __launch_bounds__(256) void cast_f32_bf16(const float* __restrict__ in,
                                                     u16* __restrict__ out) {
  size_t i = (size_t)blockIdx.x * 256 + threadIdx.x;
  typedef __attribute__((ext_vector_type(4))) float f4v;
  f4v v = ((const f4v*)in)[i];
  u16x4 o = { f2bf(v[0]), f2bf(v[1]), f2bf(v[2]), f2bf(v[3]) };
  ((u16x4*)out)[i] = o;
}

// in[K][N] fp32 -> out[N][K] bf16   (N % 256 == 0)
__global__ __launch_bounds__(256) void transpose_cast(const float* __restrict__ in,
                                                      u16* __restrict__ out, int K, int N) {
  int n = blockIdx.x * 256 + threadIdx.x;
  int k = blockIdx.y;
  out[(size_t)n * K + k] = f2bf(in[(size_t)k * N + n]);
}

// ---------------- GEMM 256x256x64, 8 waves, counted vmcnt, swizzled LDS ----------------
__device__ __forceinline__ void storeC(float* C, size_t i, float v) { C[i] = v; }
__device__ __forceinline__ void storeC(u16* C, size_t i, float v)   { C[i] = f2bf(v); }

// C[M][N] = A[M][K] * BT[N][K]^T, bf16 in, fp32 acc.
// Tile 256x256, BK=64, 512 threads (8 waves, 2Mx4N), wave output 128x64.
// LDS layout per buf: [256 rows][64 k] bf16, row = 128B = 8 granules of 16B.
// Swizzle: granule_col ^= (row & 7)  (applied on global SOURCE for staging, and on
// ds_read address — linear global_load_lds dest per rule 21).
template <typename OUT>
__global__ __launch_bounds__(512, 2) void gemm256(const u16* __restrict__ A,
                                                  const u16* __restrict__ BT,
                                                  OUT* __restrict__ C,
                                                  int M, int N, int K, int ntn) {
  __shared__ __align__(16) u16 smA[2][256 * 64];
  __shared__ __align__(16) u16 smB[2][256 * 64];
  const int tid = threadIdx.x;
  const int lane = tid & 63;
  const int w = tid >> 6;
  const int wm = w >> 2, wn = w & 3;          // wave tile: rows wm*128, cols wn*64

  int bid = blockIdx.x;
  const int cpx = gridDim.x >> 3;             // grid % 8 == 0 for all our launches
  bid = (bid & 7) * cpx + (bid >> 3);         // XCD-aware swizzle (T1)
  const int tm = (bid / ntn) << 8;
  const int tn = (bid % ntn) << 8;

  // staging: per K-tile each thread does 4 A-loads + 4 B-loads of 16B.
  // load l: granule g = l*512+tid; LDS byte g*16 (linear, wave-uniform+lane*16);
  // source col granule = (g&7) ^ (row&7).
  const u16* srcA[4]; const u16* srcB[4]; int ldsOff[4];
#pragma unroll
  for (int l = 0; l < 4; ++l) {
    const int g = l * 512 + tid;
    const int row = g >> 3, c = g & 7;
    srcA[l] = A + (size_t)(tm + row) * K + ((c ^ (row & 7)) << 3);
    srcB[l] = BT + (size_t)(tn + row) * K + ((c ^ (row & 7)) << 3);
    ldsOff[l] = g << 4;
  }

  auto STAGE = [&](int buf, int kt) {          // 8 global_load_lds
    const int k0 = kt << 6;
#pragma unroll
    for (int l = 0; l < 4; ++l) {
      gload16(srcA[l] + k0, (char*)smA[buf] + ldsOff[l]);
      gload16(srcB[l] + k0, (char*)smB[buf] + ldsOff[l]);
    }
  };

  const int swz = (lane & 7) << 4;
  const int r16 = lane & 15;
  const int kb  = (lane >> 4) << 4;            // 16B chunk within 64B k-slice
  auto LDA = [&](int buf, int fm, int ks) {    // conflict-free after swizzle
    const int off = (wm * 128 + fm * 16 + r16) * 128 + ((((ks << 6) | kb)) ^ swz);
    return *(const bf16x8*)((const char*)smA[buf] + off);
  };
  auto LDB = [&](int buf, int fn, int ks) {
    const int off = (wn * 64 + fn * 16 + r16) * 128 + ((((ks << 6) | kb)) ^ swz);
    return *(const bf16x8*)((const char*)smB[buf] + off);
  };

  f32x4 acc[8][4];
#pragma unroll
  for (int i = 0; i < 8; ++i)
#pragma unroll
    for (int j = 0; j < 4; ++j) acc[i][j] = (f32x4){0.f, 0.f, 0.f, 0.f};

  STAGE(0, 0);
  STAGE(1, 1);
  const int NT = K >> 6;                       // 16

  auto BODY = [&](int cur, int t, bool last) {
    // counted vmcnt (T4): wait for cur's 8 loads; next tile's 8 stay in flight.
    if (last) asm volatile("s_waitcnt vmcnt(0)\n\ts_barrier" ::: "memory");
    else      asm volatile("s_waitcnt vmcnt(8)\n\ts_barrier" ::: "memory");
    bf16x8 a[4][2], bl[2][2], bh[2][2];
    // ---- phase 1: read A-low quarter + B-low half; q00 = A0 x B0
#pragma unroll
    for (int fm = 0; fm < 4; ++fm) { a[fm][0] = LDA(cur, fm, 0); a[fm][1] = LDA(cur, fm, 1); }
#pragma unroll
    for (int fn = 0; fn < 2; ++fn) { bl[fn][0] = LDB(cur, fn, 0); bl[fn][1] = LDB(cur, fn, 1); }
    __builtin_amdgcn_s_barrier();
    asm volatile("s_waitcnt lgkmcnt(0)" ::: "memory");
    __builtin_amdgcn_sched_barrier(0);
    __builtin_amdgcn_s_setprio(1);
#pragma unroll
    for (int fm = 0; fm < 4; ++fm)
#pragma unroll
      for (int fn = 0; fn < 2; ++fn) {
        acc[fm][fn] = __builtin_amdgcn_mfma_f32_16x16x32_bf16(a[fm][0], bl[fn][0], acc[fm][fn], 0, 0, 0);
        acc[fm][fn] = __builtin_amdgcn_mfma_f32_16x16x32_bf16(a[fm][1], bl[fn][1], acc[fm][fn], 0, 0, 0);
      }
    __builtin_amdgcn_s_setprio(0);
    __builtin_amdgcn_s_barrier();
    // ---- phase 2: read B-high half; q01 = A0 x B1
#pragma unroll
    for (int fn = 0; fn < 2; ++fn) { bh[fn][0] = LDB(cur, 2 + fn, 0); bh[fn][1] = LDB(cur, 2 + fn, 1); }
    __builtin_amdgcn_s_barrier();
    asm volatile("s_waitcnt lgkmcnt(0)" ::: "memory");
    __builtin_amdgcn_sched_barrier(0);
    __builtin_amdgcn_s_setprio(1);
#pragma unroll
    for (int fm = 0; fm < 4; ++fm)
#pragma unroll
      for (int fn = 0; fn < 2; ++fn) {
        acc[fm][2 + fn] = __builtin_amdgcn_mfma_f32_16x16x32_bf16(a[fm][0], bh[fn][0], acc[fm][2 + fn], 0, 0, 0);
        acc[fm][2 + fn] = __builtin_amdgcn_mfma_f32_16x16x32_bf16(a[fm][1], bh[fn][1], acc[fm][2 + fn], 0, 0, 0);
      }
    __builtin_amdgcn_s_setprio(0);
    __builtin_amdgcn_s_barrier();
    // ---- phase 3: read A-high quarter (reuse regs); q10 = A1 x B1
#pragma unroll
    for (int fm = 0; fm < 4; ++fm) { a[fm][0] = LDA(cur, 4 + fm, 0); a[fm][1] = LDA(cur, 4 + fm, 1); }
    __builtin_amdgcn_s_barrier();
    asm volatile("s_waitcnt lgkmcnt(0)" ::: "memory");
    __builtin_amdgcn_sched_barrier(0);
    __builtin_amdgcn_s_setprio(1);
#pragma unroll
    for (int fm = 0; fm < 4; ++fm)
#pragma unroll
      for (int fn = 0; fn < 2; ++fn) {
        acc[4 + fm][2 + fn] = __builtin_amdgcn_mfma_f32_16x16x32_bf16(a[fm][0], bh[fn][0], acc[4 + fm][2 + fn], 0, 0, 0);
        acc[4 + fm][2 + fn] = __builtin_amdgcn_mfma_f32_16x16x32_bf16(a[fm][1], bh[fn][1], acc[4 + fm][2 + fn], 0, 0, 0);
      }
    __builtin_amdgcn_s_setprio(0);
    __builtin_amdgcn_s_barrier();
    // ---- phase 4: no reads; q11 = A1 x B0
    __builtin_amdgcn_s_setprio(1);
#pragma unroll
    for (int fm = 0; fm < 4; ++fm)
#pragma unroll
      for (int fn = 0; fn < 2; ++fn) {
        acc[4 + fm][fn] = __builtin_amdgcn_mfma_f32_16x16x32_bf16(a[fm][0], bl[fn][0], acc[4 + fm][fn], 0, 0, 0);
        acc[4 + fm][fn] = __builtin_amdgcn_mfma_f32_16x16x32_bf16(a[fm][1], bl[fn][1], acc[4 + fm][fn], 0, 0, 0);
      }
    __builtin_amdgcn_s_setprio(0);
    // end of iter: all waves done reading buf[cur]; safe to re-stage it.
    asm volatile("s_barrier" ::: "memory");
    __builtin_amdgcn_sched_barrier(0);
    if (t + 2 < NT) STAGE(cur, t + 2);
  };

  for (int t = 0; t < NT - 1; ++t) BODY(t & 1, t, false);
  BODY((NT - 1) & 1, NT - 1, true);

  // C-write: row = (lane>>4)*4+reg (A side), col = lane&15 (B side)  [m89 layout]
  const int r0 = tm + wm * 128 + ((lane >> 4) << 2);
  const int c0 = tn + wn * 64 + r16;
#pragma unroll
  for (int fm = 0; fm < 8; ++fm)
#pragma unroll
    for (int r = 0; r < 4; ++r) {
      const size_t base = (size_t)(r0 + fm * 16 + r) * N + c0;
#pragma unroll
      for (int fn = 0; fn < 4; ++fn) storeC(C, base + fn * 16, acc[fm][fn][r]);
    }
}

// ---------------- RMSNorm of q,k parts of qkv (in place, bf16) ----------------
__global__ __launch_bounds__(256) void rmsnorm_qk(u16* __restrict__ qkv,
                                                  const float* __restrict__ lnw) {
  const size_t t = blockIdx.x;
  u16* row = qkv + t * N1_;
  const int tid = threadIdx.x;
  __shared__ float red[4];
#pragma unroll
  for (int part = 0; part < 2; ++part) {
    u16* p = row + part * C_;
    u16x4 v = ((const u16x4*)p)[tid];
    float f0 = bf2f(v[0]), f1 = bf2f(v[1]), f2 = bf2f(v[2]), f3 = bf2f(v[3]);
    float ss = f0 * f0 + f1 * f1 + f2 * f2 + f3 * f3;
#pragma unroll
    for (int o = 1; o < 64; o <<= 1) ss += __shfl_xor(ss, o, 64);
    if ((tid & 63) == 0) red[tid >> 6] = ss;
    __syncthreads();
    float sc = rsqrtf((red[0] + red[1] + red[2] + red[3]) * (1.0f / 1024.0f) + 1e-6f);
    const int c = tid * 4;
    u16x4 o4 = { f2bf(f0 * sc * lnw[c]), f2bf(f1 * sc * lnw[c + 1]),
                 f2bf(f2 * sc * lnw[c + 2]), f2bf(f3 * sc * lnw[c + 3]) };
    ((u16x4*)p)[tid] = o4;
    __syncthreads();
  }
}

// ---------------- block-causal attention ----------------
__global__ __launch_bounds__(256, 1) void attn_kernel(const u16* __restrict__ qkv,
                                                      u16* __restrict__ y) {
  const int bid = blockIdx.x;
  const int h = bid & 15;
  const int bg = bid >> 4;
  const size_t rowbase = (size_t)bg * 256;
  const u16* Qg = qkv + rowbase * N1_ + h * 64;
  const u16* Kg = Qg + C_;
  const u16* Vg = Qg + 2 * C_;

  __shared__ __align__(16) u16 Ks[256 * 64];       // [k_tok][hd], XOR-swizzled
  __shared__ __align__(16) u16 Vt[64 * 256];       // [hd][k_tok], XOR-swizzled
  __shared__ __align__(16) u16 Ps[4][16 * 256];    // per-wave P [q][k], XOR-swizzled

  const int tid = threadIdx.x;
  const int lane = tid & 63;
  const int w = tid >> 6;
  const int g = lane >> 4;
  const int qi = lane & 15;

  {
    const int r = tid;
    const u16* kr = Kg + (size_t)r * N1_;
    const u16* vr = Vg + (size_t)r * N1_;
    char* ksb = (char*)Ks + r * 128;
    const int swk = (r & 7) << 4;
#pragma unroll
    for (int j = 0; j < 8; ++j) {
      bf16x8 kv = *(const bf16x8*)(kr + j * 8);
      *(bf16x8*)(ksb + ((j * 16) ^ swk)) = kv;
      bf16x8 vv = *(const bf16x8*)(vr + j * 8);
#pragma unroll
      for (int e = 0; e < 8; ++e) {
        int d = j * 8 + e;
        *(u16*)((char*)Vt + d * 512 + ((2 * r) ^ ((d & 7) << 4))) = (u16)vv[e];
      }
    }
  }
  __syncthreads();

  const float scale = 0.125f;
  char* pb = (char*)Ps[w];
  const int swq = (qi & 7) << 4;

#pragma unroll 1
  for (int qt = w; qt < 16; qt += 4) {
    const u16* qrow = Qg + (size_t)(qt * 16 + qi) * N1_ + g * 8;
    bf16x8 q0 = *(const bf16x8*)(qrow);
    bf16x8 q1 = *(const bf16x8*)(qrow + 32);

    f32x4 s[16];
#pragma unroll
    for (int n = 0; n < 16; ++n) {
      if (n <= qt) {
        const char* kb = (const char*)Ks + (n * 16 + qi) * 128;
        bf16x8 ka0 = *(const bf16x8*)(kb + ((g * 16) ^ swq));
        bf16x8 ka1 = *(const bf16x8*)(kb + ((g * 16 + 64) ^ swq));
        f32x4 a = {0.f, 0.f, 0.f, 0.f};
        a = __builtin_amdgcn_mfma_f32_16x16x32_bf16(ka0, q0, a, 0, 0, 0);
        a = __builtin_amdgcn_mfma_f32_16x16x32_bf16(ka1, q1, a, 0, 0, 0);
        s[n] = a;
      }
    }

    const int q_abs = qt * 16 + qi;
    float m = -3e38f;
#pragma unroll
    for (int n = 0; n < 16; ++n) if (n <= qt) {
#pragma unroll
      for (int r = 0; r < 4; ++r) {
        const int k_abs = n * 16 + g * 4 + r;
        float v = s[n][r] * scale;
        v = (k_abs <= q_abs) ? v : -3e38f;
        s[n][r] = v;
        m = fmaxf(m, v);
      }
    }
    m = fmaxf(m, __shfl_xor(m, 16, 64));
    m = fmaxf(m, __shfl_xor(m, 32, 64));

    float sum = 0.f;
#pragma unroll
    for (int n = 0; n < 16; ++n) if (n <= qt) {
#pragma unroll
      for (int r = 0; r < 4; ++r) {
        float p = __expf(s[n][r] - m);
        s[n][r] = p;
        sum += p;
      }
    }
    sum += __shfl_xor(sum, 16, 64);
    sum += __shfl_xor(sum, 32, 64);

#pragma unroll
    for (int n = 0; n < 16; ++n) if (n <= qt) {
      u16x4 pk = { f2bf(s[n][0]), f2bf(s[n][1]), f2bf(s[n][2]), f2bf(s[n][3]) };
      *(u16x4*)(pb + qi * 512 + ((n * 32 + g * 8) ^ swq)) = pk;
    }
    if (!(qt & 1)) {
      u16x4 z = {0, 0, 0, 0};
      *(u16x4*)(pb + qi * 512 + (((qt + 1) * 32 + g * 8) ^ swq)) = z;
    }

    f32x4 yacc[4];
#pragma unroll
    for (int dn = 0; dn < 4; ++dn) yacc[dn] = (f32x4){0.f, 0.f, 0.f, 0.f};
    const int nkf = qt / 2 + 1;
#pragma unroll
    for (int kf = 0; kf < 8; ++kf) if (kf < nkf) {
      bf16x8 pa = *(const bf16x8*)(pb + qi * 512 + ((kf * 64 + g * 16) ^ swq));
#pragma unroll
      for (int dn = 0; dn < 4; ++dn) {
        const int d = dn * 16 + qi;
        bf16x8 vb = *(const bf16x8*)((const char*)Vt + d * 512 + ((kf * 64 + g * 16) ^ swq));
        yacc[dn] = __builtin_amdgcn_mfma_f32_16x16x32_bf16(pa, vb, yacc[dn], 0, 0, 0);
      }
    }

#pragma unroll
    for (int r = 0; r < 4; ++r) {
      const float inv = 1.0f / __shfl(sum, g * 4 + r, 64);
      const size_t trow = rowbase + (size_t)qt * 16 + g * 4 + r;
      u16* yrow = y + trow * C_ + h * 64 + qi;
#pragma unroll
      for (int dn = 0; dn < 4; ++dn) yrow[dn * 16] = f2bf(yacc[dn][r] * inv);
    }
  }
}

// ---------------- launch ----------------
extern "C" void kernel_launch(void* const* d_in, const int* in_sizes, int n_in,
                              void* d_out, int out_size, void* d_ws, size_t ws_size,
                              hipStream_t stream) {
  const float* x      = (const float*)d_in[0];   // [16384][1024]
  const float* w_qkv  = (const float*)d_in[1];   // [1024][3072]
  const float* ln_w   = (const float*)d_in[2];   // [1024]
  const float* w_proj = (const float*)d_in[3];   // [1024][1024]
  float* out = (float*)d_out;                    // [16384][1024] fp32

  u16* xb     = (u16*)d_ws;                          // 16384*1024
  u16* wqkvT  = xb + (size_t)M_ * C_;                // 3072*1024 (transposed)
  u16* wprojT = wqkvT + (size_t)N1_ * C_;            // 1024*1024 (transposed)
  u16* qkvb   = wprojT + (size_t)C_ * C_;            // 16384*3072
  u16* yb     = qkvb + (size_t)M_ * N1_;             // 16384*1024

  cast_f32_bf16<<<(M_ * C_) / 1024, 256, 0, stream>>>(x, xb);
  transpose_cast<<<dim3(N1_ / 256, C_), 256, 0, stream>>>(w_qkv, wqkvT, C_, N1_);
  transpose_cast<<<dim3(C_ / 256, C_), 256, 0, stream>>>(w_proj, wprojT, C_, C_);

  gemm256<u16><<<(M_ / 256) * (N1_ / 256), 512, 0, stream>>>(xb, wqkvT, qkvb, M_, N1_, C_, N1_ / 256);
  rmsnorm_qk<<<M_, 256, 0, stream>>>(qkvb, ln_w);
  attn_kernel<<<64 * 16, 256, 0, stream>>>(qkvb, yb);
  gemm256<float><<<(M_ / 256) * (C_ / 256), 512, 0, stream>>>(yb, wprojT, out, M_, C_, C_, C_ / 256);
}

// Round 3
// 293.693 us; speedup vs baseline: 1.1572x; 1.1222x over previous
//
#include <hip/hip_runtime.h>

typedef __attribute__((ext_vector_type(4))) float f32x4;
typedef __attribute__((ext_vector_type(8))) short bf16x8;
typedef __attribute__((ext_vector_type(4))) unsigned short u16x4;
typedef __attribute__((ext_vector_type(8))) unsigned short u16x8;
typedef unsigned short u16;
typedef unsigned int u32;

// B=4 T=4096 C=1024 H=16 LS=256
#define M_  16384   // B*T
#define C_  1024
#define N1_ 3072    // 3C

__device__ __forceinline__ float bf2f(u16 u) {
  union { u32 i; float f; } v; v.i = ((u32)u) << 16; return v.f;
}
__device__ __forceinline__ u16 f2bf(float f) {
  union { float f; u32 i; } v; v.f = f;
  u32 r = v.i + 0x7fffu + ((v.i >> 16) & 1u);   // RN-even
  return (u16)(r >> 16);
}

__device__ __forceinline__ void gload16(const void* g, void* l) {
  __builtin_amdgcn_global_load_lds(
      (const __attribute__((address_space(1))) u32*)g,
      (__attribute__((address_space(3))) u32*)l, 16, 0, 0);
}

// ---------------- casts ----------------
__global__ __launch_bounds__(256) void cast_f32_bf16(const float* __restrict__ in,
                                                     u16* __restrict__ out) {
  size_t i = (size_t)blockIdx.x * 256 + threadIdx.x;
  f32x4 v = ((const f32x4*)in)[i];
  u16x4 o = { f2bf(v[0]), f2bf(v[1]), f2bf(v[2]), f2bf(v[3]) };
  ((u16x4*)out)[i] = o;
}

// in[K][N] fp32 -> out[N][K] bf16, LDS-tiled 64x64, coalesced both sides
__global__ __launch_bounds__(256) void transpose_cast(const float* __restrict__ in,
                                                      u16* __restrict__ out, int K, int N) {
  __shared__ u16 tile[64][65];
  const int n0 = blockIdx.x * 64, k0 = blockIdx.y * 64;
  const int tid = threadIdx.x;
  const int nn = tid & 63, kk = tid >> 6;
#pragma unroll
  for (int r = 0; r < 16; ++r)
    tile[kk * 16 + r][nn] = f2bf(in[(size_t)(k0 + kk * 16 + r) * N + n0 + nn]);
  __syncthreads();
  const int kc = tid & 15, nl = tid >> 4;
#pragma unroll
  for (int p = 0; p < 4; ++p) {
    const int n = p * 16 + nl;
    u16x4 v = { tile[kc * 4 + 0][n], tile[kc * 4 + 1][n],
                tile[kc * 4 + 2][n], tile[kc * 4 + 3][n] };
    *(u16x4*)(out + (size_t)(n0 + n) * K + k0 + kc * 4) = v;
  }
}

// ---------------- GEMM 256x256, BK=64, static-parity double buffer ----------------
__device__ __forceinline__ void store16(float* dst, f32x4 v0, f32x4 v1, f32x4 v2, f32x4 v3) {
  ((f32x4*)dst)[0] = v0; ((f32x4*)dst)[1] = v1; ((f32x4*)dst)[2] = v2; ((f32x4*)dst)[3] = v3;
}
__device__ __forceinline__ void store16(u16* dst, f32x4 v0, f32x4 v1, f32x4 v2, f32x4 v3) {
  u16x8 o0 = { f2bf(v0[0]), f2bf(v0[1]), f2bf(v0[2]), f2bf(v0[3]),
               f2bf(v1[0]), f2bf(v1[1]), f2bf(v1[2]), f2bf(v1[3]) };
  u16x8 o1 = { f2bf(v2[0]), f2bf(v2[1]), f2bf(v2[2]), f2bf(v2[3]),
               f2bf(v3[0]), f2bf(v3[1]), f2bf(v3[2]), f2bf(v3[3]) };
  *(u16x8*)dst = o0; *(u16x8*)(dst + 8) = o1;
}

// C[M][N] = A[M][K=1024] * BT[N][K]^T, bf16 in, fp32 acc. 512 thr (8 waves 2Mx4N).
template <typename OUT>
__global__ __launch_bounds__(512, 2) void gemm256(const u16* __restrict__ A,
                                                  const u16* __restrict__ BT,
                                                  OUT* __restrict__ C,
                                                  int M, int N, int ntn) {
  constexpr int KC = 1024;
  __shared__ __align__(16) u16 sA0[256 * 64], sA1[256 * 64];
  __shared__ __align__(16) u16 sB0[256 * 64], sB1[256 * 64];
  const int tid = threadIdx.x, lane = tid & 63, w = tid >> 6;
  const int wm = w >> 2, wn = w & 3;

  int bid = blockIdx.x;
  const int cpx = gridDim.x >> 3;              // grid % 8 == 0 for all our launches
  bid = (bid & 7) * cpx + (bid >> 3);          // XCD swizzle (T1)
  const int tm = (bid / ntn) << 8, tn = (bid % ntn) << 8;

  // staging addresses: granule g = l*512+tid -> LDS byte g*16 (linear);
  // source granule col = (g&7) ^ (row&7)  (pre-swizzled source, rule 21)
  const u16* srcA[4]; const u16* srcB[4]; int ldsOff[4];
#pragma unroll
  for (int l = 0; l < 4; ++l) {
    const int g = l * 512 + tid;
    const int row = g >> 3, c = g & 7;
    srcA[l] = A + (size_t)(tm + row) * KC + ((c ^ (row & 7)) << 3);
    srcB[l] = BT + (size_t)(tn + row) * KC + ((c ^ (row & 7)) << 3);
    ldsOff[l] = g << 4;
  }

#define STAGE(sa, sb, kt) do { const int _k0 = (kt) << 6;                      \
    _Pragma("unroll") for (int _l = 0; _l < 4; ++_l) {                         \
      gload16(srcA[_l] + _k0, (char*)(sa) + ldsOff[_l]);                       \
      gload16(srcB[_l] + _k0, (char*)(sb) + ldsOff[_l]); } } while (0)

  const int swz = (lane & 7) << 4;
  const int r16 = lane & 15;
  const int kb = (lane >> 4) << 4;
#define LDA_(sa, fm, ks) (*(const bf16x8*)((const char*)(sa) + \
    (wm * 128 + (fm) * 16 + r16) * 128 + ((((ks) << 6) | kb) ^ swz)))
#define LDB_(sb, fn, ks) (*(const bf16x8*)((const char*)(sb) + \
    (wn * 64 + (fn) * 16 + r16) * 128 + ((((ks) << 6) | kb) ^ swz)))

  f32x4 acc[8][4];
#pragma unroll
  for (int i = 0; i < 8; ++i)
#pragma unroll
    for (int j = 0; j < 4; ++j) acc[i][j] = (f32x4){0.f, 0.f, 0.f, 0.f};

#define MM(i, j, a_, b_) acc[i][j] = __builtin_amdgcn_mfma_f32_16x16x32_bf16(a_, b_, acc[i][j], 0, 0, 0)

// one K-tile = 4 phases; STG (prefetch into this tile's buffers) issues in phase 4,
// after phase-3's closing barrier guarantees all waves finished reading them.
#define KTILE(sa, sb, ...) do {                                                \
  bf16x8 ka[4][2], kb0[2][2], kb1[2][2];                                       \
  _Pragma("unroll") for (int fm = 0; fm < 4; ++fm) {                           \
    ka[fm][0] = LDA_(sa, fm, 0); ka[fm][1] = LDA_(sa, fm, 1); }                \
  _Pragma("unroll") for (int fn = 0; fn < 2; ++fn) {                           \
    kb0[fn][0] = LDB_(sb, fn, 0); kb0[fn][1] = LDB_(sb, fn, 1); }              \
  __builtin_amdgcn_s_barrier();                                                \
  __builtin_amdgcn_s_setprio(1);                                               \
  _Pragma("unroll") for (int fm = 0; fm < 4; ++fm)                             \
    _Pragma("unroll") for (int fn = 0; fn < 2; ++fn) {                         \
      MM(fm, fn, ka[fm][0], kb0[fn][0]); MM(fm, fn, ka[fm][1], kb0[fn][1]); }  \
  __builtin_amdgcn_s_setprio(0);                                               \
  __builtin_amdgcn_s_barrier();                                                \
  _Pragma("unroll") for (int fn = 0; fn < 2; ++fn) {                           \
    kb1[fn][0] = LDB_(sb, 2 + fn, 0); kb1[fn][1] = LDB_(sb, 2 + fn, 1); }      \
  __builtin_amdgcn_s_barrier();                                                \
  __builtin_amdgcn_s_setprio(1);                                               \
  _Pragma("unroll") for (int fm = 0; fm < 4; ++fm)                             \
    _Pragma("unroll") for (int fn = 0; fn < 2; ++fn) {                         \
      MM(fm, 2 + fn, ka[fm][0], kb1[fn][0]); MM(fm, 2 + fn, ka[fm][1], kb1[fn][1]); } \
  __builtin_amdgcn_s_setprio(0);                                               \
  __builtin_amdgcn_s_barrier();                                                \
  _Pragma("unroll") for (int fm = 0; fm < 4; ++fm) {                           \
    ka[fm][0] = LDA_(sa, 4 + fm, 0); ka[fm][1] = LDA_(sa, 4 + fm, 1); }        \
  __builtin_amdgcn_s_barrier();                                                \
  __builtin_amdgcn_s_setprio(1);                                               \
  _Pragma("unroll") for (int fm = 0; fm < 4; ++fm)                             \
    _Pragma("unroll") for (int fn = 0; fn < 2; ++fn) {                         \
      MM(4 + fm, 2 + fn, ka[fm][0], kb1[fn][0]); MM(4 + fm, 2 + fn, ka[fm][1], kb1[fn][1]); } \
  __builtin_amdgcn_s_setprio(0);                                               \
  __builtin_amdgcn_s_barrier();                                                \
  __builtin_amdgcn_sched_barrier(0);                                           \
  __VA_ARGS__;                                                                 \
  __builtin_amdgcn_s_setprio(1);                                               \
  _Pragma("unroll") for (int fm = 0; fm < 4; ++fm)                             \
    _Pragma("unroll") for (int fn = 0; fn < 2; ++fn) {                         \
      MM(4 + fm, fn, ka[fm][0], kb0[fn][0]); MM(4 + fm, fn, ka[fm][1], kb0[fn][1]); } \
  __builtin_amdgcn_s_setprio(0);                                               \
} while (0)

#define TILE_ENTRY(vm) do { __builtin_amdgcn_sched_barrier(0);                 \
    asm volatile("s_waitcnt vmcnt(" #vm ")");                                  \
    __builtin_amdgcn_sched_barrier(0);                                         \
    __builtin_amdgcn_s_barrier();                                              \
    __builtin_amdgcn_sched_barrier(0); } while (0)

  STAGE(sA0, sB0, 0);
  STAGE(sA1, sB1, 1);

#pragma unroll 1
  for (int i = 0; i < 7; ++i) {
    TILE_ENTRY(8);
    KTILE(sA0, sB0, STAGE(sA0, sB0, 2 * i + 2));
    TILE_ENTRY(8);
    KTILE(sA1, sB1, STAGE(sA1, sB1, 2 * i + 3));
  }
  TILE_ENTRY(8);
  KTILE(sA0, sB0, (void)0);
  TILE_ENTRY(0);
  KTILE(sA1, sB1, (void)0);

  // ---- epilogue: per-wave LDS repack -> coalesced wide stores ----
  __syncthreads();
  u16* eb = (w == 0) ? sA0 : (w == 1) ? sA0 + 8192 : (w == 2) ? sA1 : (w == 3) ? sA1 + 8192
          : (w == 4) ? sB0 : (w == 5) ? sB0 + 8192 : (w == 6) ? sB1 : sB1 + 8192;
  float* fb = (float*)eb;                       // 16 x 68 f32 region per wave
  const int erow = lane >> 2, eseg = lane & 3;
#pragma unroll
  for (int fm = 0; fm < 8; ++fm) {
#pragma unroll
    for (int fn = 0; fn < 4; ++fn)
#pragma unroll
      for (int r = 0; r < 4; ++r)
        fb[((lane >> 4) * 4 + r) * 68 + fn * 16 + (lane & 15)] = acc[fm][fn][r];
    asm volatile("s_waitcnt lgkmcnt(0)" ::: "memory");
    const float* src = &fb[erow * 68 + eseg * 16];
    f32x4 v0 = ((const f32x4*)src)[0], v1 = ((const f32x4*)src)[1];
    f32x4 v2 = ((const f32x4*)src)[2], v3 = ((const f32x4*)src)[3];
    OUT* dst = C + (size_t)(tm + wm * 128 + fm * 16 + erow) * N + tn + wn * 64 + eseg * 16;
    store16(dst, v0, v1, v2, v3);
  }
#undef STAGE
#undef LDA_
#undef LDB_
#undef MM
#undef KTILE
#undef TILE_ENTRY
}

// ---------------- per-token q/k RMS scale factors ----------------
__global__ __launch_bounds__(256) void qk_scales(const u16* __restrict__ qkv,
                                                 float* __restrict__ qscl,
                                                 float* __restrict__ kscl) {
  const int t = blockIdx.x * 4 + (threadIdx.x >> 6);
  const int lane = threadIdx.x & 63;
  const u16* row = qkv + (size_t)t * N1_;
#pragma unroll
  for (int part = 0; part < 2; ++part) {
    const u16* p = row + part * C_ + lane * 16;
    bf16x8 v0 = *(const bf16x8*)p;
    bf16x8 v1 = *(const bf16x8*)(p + 8);
    float ss = 0.f;
#pragma unroll
    for (int e = 0; e < 8; ++e) {
      float a = bf2f((u16)v0[e]), b = bf2f((u16)v1[e]);
      ss += a * a + b * b;
    }
#pragma unroll
    for (int o = 1; o < 64; o <<= 1) ss += __shfl_xor(ss, o, 64);
    if (lane == 0) {
      float s = rsqrtf(ss * (1.0f / 1024.0f) + 1e-6f);
      (part ? kscl : qscl)[t] = s;
    }
  }
}

// ---------------- block-causal attention (RMS scales + ln_w fused) ----------------
__global__ __launch_bounds__(256, 1) void attn_kernel(const u16* __restrict__ qkv,
                                                      const float* __restrict__ qscl,
                                                      const float* __restrict__ kscl,
                                                      const float* __restrict__ lnw,
                                                      u16* __restrict__ y) {
  const int bid = blockIdx.x;
  const int h = bid & 15;
  const int bg = bid >> 4;
  const size_t rowbase = (size_t)bg * 256;
  const u16* Qg = qkv + rowbase * N1_ + h * 64;
  const u16* Kg = Qg + C_;
  const u16* Vg = Qg + 2 * C_;

  __shared__ __align__(16) u16 Ks[256 * 64];       // [k_tok][hd], XOR-swizzled
  __shared__ __align__(16) u16 Vt[64 * 256];       // [hd][k_tok], XOR-swizzled
  __shared__ __align__(16) u16 Ps[4][16 * 256];    // per-wave P [q][k], XOR-swizzled

  const int tid = threadIdx.x;
  const int lane = tid & 63;
  const int w = tid >> 6;
  const int g = lane >> 4;
  const int qi = lane & 15;

  // load K (scaled by kscl * lnw), V: one token row per thread
  {
    const int r = tid;
    const u16* kr = Kg + (size_t)r * N1_;
    const u16* vr = Vg + (size_t)r * N1_;
    const float ksc = kscl[rowbase + r];
    const float* lw = lnw + h * 64;
    char* ksb = (char*)Ks + r * 128;
    const int swk = (r & 7) << 4;
#pragma unroll
    for (int j = 0; j < 8; ++j) {
      bf16x8 kv = *(const bf16x8*)(kr + j * 8);
      f32x4 wa = *(const f32x4*)(lw + j * 8);
      f32x4 wb = *(const f32x4*)(lw + j * 8 + 4);
#pragma unroll
      for (int e = 0; e < 4; ++e) {
        kv[e]     = (short)f2bf(bf2f((u16)kv[e]) * ksc * wa[e]);
        kv[4 + e] = (short)f2bf(bf2f((u16)kv[4 + e]) * ksc * wb[e]);
      }
      *(bf16x8*)(ksb + ((j * 16) ^ swk)) = kv;
      bf16x8 vv = *(const bf16x8*)(vr + j * 8);
#pragma unroll
      for (int e = 0; e < 8; ++e) {
        int d = j * 8 + e;
        *(u16*)((char*)Vt + d * 512 + ((2 * r) ^ ((d & 7) << 4))) = (u16)vv[e];
      }
    }
  }
  // per-lane ln_w factors for the Q fragment columns
  float lnq0[8], lnq1[8];
#pragma unroll
  for (int e = 0; e < 8; ++e) {
    lnq0[e] = lnw[h * 64 + g * 8 + e];
    lnq1[e] = lnw[h * 64 + 32 + g * 8 + e];
  }
  __syncthreads();

  const float scale = 0.125f;
  char* pb = (char*)Ps[w];
  const int swq = (qi & 7) << 4;

#pragma unroll 1
  for (int j = 0; j < 4; ++j) {
    // balanced tile set: {w, 7-w, 8+w, 15-w} -> equal causal work per wave
    const int qt = ((j >> 1) << 3) + ((j & 1) ? (7 - w) : w);

    const u16* qrow = Qg + (size_t)(qt * 16 + qi) * N1_ + g * 8;
    const float qsc = qscl[rowbase + qt * 16 + qi];
    bf16x8 q0 = *(const bf16x8*)(qrow);
    bf16x8 q1 = *(const bf16x8*)(qrow + 32);
#pragma unroll
    for (int e = 0; e < 8; ++e) {
      q0[e] = (short)f2bf(bf2f((u16)q0[e]) * qsc * lnq0[e]);
      q1[e] = (short)f2bf(bf2f((u16)q1[e]) * qsc * lnq1[e]);
    }

    f32x4 s[16];
#pragma unroll
    for (int n = 0; n < 16; ++n) {
      if (n <= qt) {
        const char* kb = (const char*)Ks + (n * 16 + qi) * 128;
        bf16x8 ka0 = *(const bf16x8*)(kb + ((g * 16) ^ swq));
        bf16x8 ka1 = *(const bf16x8*)(kb + ((g * 16 + 64) ^ swq));
        f32x4 a = {0.f, 0.f, 0.f, 0.f};
        a = __builtin_amdgcn_mfma_f32_16x16x32_bf16(ka0, q0, a, 0, 0, 0);
        a = __builtin_amdgcn_mfma_f32_16x16x32_bf16(ka1, q1, a, 0, 0, 0);
        s[n] = a;
      }
    }

    const int q_abs = qt * 16 + qi;
    float m = -3e38f;
#pragma unroll
    for (int n = 0; n < 16; ++n) if (n <= qt) {
#pragma unroll
      for (int r = 0; r < 4; ++r) {
        const int k_abs = n * 16 + g * 4 + r;
        float v = s[n][r] * scale;
        v = (k_abs <= q_abs) ? v : -3e38f;
        s[n][r] = v;
        m = fmaxf(m, v);
      }
    }
    m = fmaxf(m, __shfl_xor(m, 16, 64));
    m = fmaxf(m, __shfl_xor(m, 32, 64));

    float sum = 0.f;
#pragma unroll
    for (int n = 0; n < 16; ++n) if (n <= qt) {
#pragma unroll
      for (int r = 0; r < 4; ++r) {
        float p = __expf(s[n][r] - m);
        s[n][r] = p;
        sum += p;
      }
    }
    sum += __shfl_xor(sum, 16, 64);
    sum += __shfl_xor(sum, 32, 64);

#pragma unroll
    for (int n = 0; n < 16; ++n) if (n <= qt) {
      u16x4 pk = { f2bf(s[n][0]), f2bf(s[n][1]), f2bf(s[n][2]), f2bf(s[n][3]) };
      *(u16x4*)(pb + qi * 512 + ((n * 32 + g * 8) ^ swq)) = pk;
    }
    if (!(qt & 1)) {   // zero-pad k-tile qt+1 (read by the last 32-wide mfma)
      u16x4 z = {0, 0, 0, 0};
      *(u16x4*)(pb + qi * 512 + (((qt + 1) * 32 + g * 8) ^ swq)) = z;
    }

    f32x4 yacc[4];
#pragma unroll
    for (int dn = 0; dn < 4; ++dn) yacc[dn] = (f32x4){0.f, 0.f, 0.f, 0.f};
    const int nkf = qt / 2 + 1;
#pragma unroll
    for (int kf = 0; kf < 8; ++kf) if (kf < nkf) {
      bf16x8 pa = *(const bf16x8*)(pb + qi * 512 + ((kf * 64 + g * 16) ^ swq));
#pragma unroll
      for (int dn = 0; dn < 4; ++dn) {
        const int d = dn * 16 + qi;
        bf16x8 vb = *(const bf16x8*)((const char*)Vt + d * 512 + ((kf * 64 + g * 16) ^ swq));
        yacc[dn] = __builtin_amdgcn_mfma_f32_16x16x32_bf16(pa, vb, yacc[dn], 0, 0, 0);
      }
    }

#pragma unroll
    for (int r = 0; r < 4; ++r) {
      const float inv = 1.0f / __shfl(sum, g * 4 + r, 64);
      const size_t trow = rowbase + (size_t)qt * 16 + g * 4 + r;
      u16* yrow = y + trow * C_ + h * 64 + qi;
#pragma unroll
      for (int dn = 0; dn < 4; ++dn) yrow[dn * 16] = f2bf(yacc[dn][r] * inv);
    }
  }
}

// ---------------- launch ----------------
extern "C" void kernel_launch(void* const* d_in, const int* in_sizes, int n_in,
                              void* d_out, int out_size, void* d_ws, size_t ws_size,
                              hipStream_t stream) {
  const float* x      = (const float*)d_in[0];   // [16384][1024]
  const float* w_qkv  = (const float*)d_in[1];   // [1024][3072]
  const float* ln_w   = (const float*)d_in[2];   // [1024]
  const float* w_proj = (const float*)d_in[3];   // [1024][1024]
  float* out = (float*)d_out;                    // [16384][1024] fp32

  u16* xb     = (u16*)d_ws;                          // 16384*1024
  u16* wqkvT  = xb + (size_t)M_ * C_;                // 3072*1024 (transposed)
  u16* wprojT = wqkvT + (size_t)N1_ * C_;            // 1024*1024 (transposed)
  u16* qkvb   = wprojT + (size_t)C_ * C_;            // 16384*3072
  u16* yb     = qkvb + (size_t)M_ * N1_;             // 16384*1024
  float* qscl = (float*)(yb + (size_t)M_ * C_);      // 16384 f32
  float* kscl = qscl + M_;                           // 16384 f32

  cast_f32_bf16<<<(M_ * C_) / 1024, 256, 0, stream>>>(x, xb);
  transpose_cast<<<dim3(N1_ / 64, C_ / 64), 256, 0, stream>>>(w_qkv, wqkvT, C_, N1_);
  transpose_cast<<<dim3(C_ / 64, C_ / 64), 256, 0, stream>>>(w_proj, wprojT, C_, C_);

  gemm256<u16><<<(M_ / 256) * (N1_ / 256), 512, 0, stream>>>(xb, wqkvT, qkvb, M_, N1_, N1_ / 256);
  qk_scales<<<M_ / 4, 256, 0, stream>>>(qkvb, qscl, kscl);
  attn_kernel<<<64 * 16, 256, 0, stream>>>(qkvb, qscl, kscl, ln_w, yb);
  gemm256<float><<<(M_ / 256) * (C_ / 256), 512, 0, stream>>>(yb, wprojT, out, M_, C_, C_ / 256);
}

// Round 4
// 258.491 us; speedup vs baseline: 1.3148x; 1.1362x over previous
//
#include <hip/hip_runtime.h>

typedef __attribute__((ext_vector_type(4))) float f32x4;
typedef __attribute__((ext_vector_type(8))) short bf16x8;
typedef __attribute__((ext_vector_type(4))) unsigned short u16x4;
typedef __attribute__((ext_vector_type(8))) unsigned short u16x8;
typedef unsigned short u16;
typedef unsigned int u32;

// B=4 T=4096 C=1024 H=16 LS=256
#define M_  16384   // B*T
#define C_  1024
#define N1_ 3072    // 3C
#define PSZ ((size_t)M_ * 64 * 16 / 16 * 4 / 4)   // 16384*1024 elements per q/k/v part

__device__ __forceinline__ float bf2f(u16 u) {
  union { u32 i; float f; } v; v.i = ((u32)u) << 16; return v.f;
}
__device__ __forceinline__ u16 f2bf(float f) {
  union { float f; u32 i; } v; v.f = f;
  u32 r = v.i + 0x7fffu + ((v.i >> 16) & 1u);   // RN-even
  return (u16)(r >> 16);
}

__device__ __forceinline__ void gload16(const void* g, void* l) {
  __builtin_amdgcn_global_load_lds(
      (const __attribute__((address_space(1))) u32*)g,
      (__attribute__((address_space(3))) u32*)l, 16, 0, 0);
}

// ---------------- casts ----------------
__global__ __launch_bounds__(256) void cast_f32_bf16(const float* __restrict__ in,
                                                     u16* __restrict__ out) {
  size_t i = (size_t)blockIdx.x * 256 + threadIdx.x;
  f32x4 v = ((const f32x4*)in)[i];
  u16x4 o = { f2bf(v[0]), f2bf(v[1]), f2bf(v[2]), f2bf(v[3]) };
  ((u16x4*)out)[i] = o;
}

// in[K][N] fp32 -> out[N][K] bf16, LDS-tiled 64x64, coalesced both sides
__global__ __launch_bounds__(256) void transpose_cast(const float* __restrict__ in,
                                                      u16* __restrict__ out, int K, int N) {
  __shared__ u16 tile[64][65];
  const int n0 = blockIdx.x * 64, k0 = blockIdx.y * 64;
  const int tid = threadIdx.x;
  const int nn = tid & 63, kk = tid >> 6;
#pragma unroll
  for (int r = 0; r < 16; ++r)
    tile[kk * 16 + r][nn] = f2bf(in[(size_t)(k0 + kk * 16 + r) * N + n0 + nn]);
  __syncthreads();
  const int kc = tid & 15, nl = tid >> 4;
#pragma unroll
  for (int p = 0; p < 4; ++p) {
    const int n = p * 16 + nl;
    u16x4 v = { tile[kc * 4 + 0][n], tile[kc * 4 + 1][n],
                tile[kc * 4 + 2][n], tile[kc * 4 + 3][n] };
    *(u16x4*)(out + (size_t)(n0 + n) * K + k0 + kc * 4) = v;
  }
}

// ---------------- GEMM 256x256, BK=64, static-parity double buffer ----------------
__device__ __forceinline__ void store16(float* dst, f32x4 v0, f32x4 v1, f32x4 v2, f32x4 v3) {
  ((f32x4*)dst)[0] = v0; ((f32x4*)dst)[1] = v1; ((f32x4*)dst)[2] = v2; ((f32x4*)dst)[3] = v3;
}
__device__ __forceinline__ void store16(u16* dst, f32x4 v0, f32x4 v1, f32x4 v2, f32x4 v3) {
  u16x8 o0 = { f2bf(v0[0]), f2bf(v0[1]), f2bf(v0[2]), f2bf(v0[3]),
               f2bf(v1[0]), f2bf(v1[1]), f2bf(v1[2]), f2bf(v1[3]) };
  u16x8 o1 = { f2bf(v2[0]), f2bf(v2[1]), f2bf(v2[2]), f2bf(v2[3]),
               f2bf(v3[0]), f2bf(v3[1]), f2bf(v3[2]), f2bf(v3[3]) };
  *(u16x8*)dst = o0; *(u16x8*)(dst + 8) = o1;
}

// C = A[M][1024] * BT[N][1024]^T, bf16 in, fp32 acc. 512 thr (8 waves 2Mx4N).
// OUT=u16: C is the head-blocked QKV base [part][bg][h][256][64]; also writes
//          per-token sum-of-squares partials for q/k parts (ssq/ssk [t][4]).
// OUT=float: row-major C[M][N] (final output).
template <typename OUT>
__global__ __launch_bounds__(512, 2) void gemm256(const u16* __restrict__ A,
                                                  const u16* __restrict__ BT,
                                                  OUT* __restrict__ C,
                                                  int M, int N, int ntn,
                                                  float* __restrict__ ssq,
                                                  float* __restrict__ ssk) {
  constexpr int KC = 1024;
  __shared__ __align__(16) u16 sA0[256 * 64], sA1[256 * 64];
  __shared__ __align__(16) u16 sB0[256 * 64], sB1[256 * 64];
  __shared__ float ssred[4][256];
  const int tid = threadIdx.x, lane = tid & 63, w = tid >> 6;
  const int wm = w >> 2, wn = w & 3;

  int bid = blockIdx.x;
  const int cpx = gridDim.x >> 3;              // grid % 8 == 0 for all our launches
  bid = (bid & 7) * cpx + (bid >> 3);          // XCD swizzle (T1)
  const int tm = (bid / ntn) << 8, tn = (bid % ntn) << 8;

  const u16* srcA[4]; const u16* srcB[4]; int ldsOff[4];
#pragma unroll
  for (int l = 0; l < 4; ++l) {
    const int g = l * 512 + tid;
    const int row = g >> 3, c = g & 7;
    srcA[l] = A + (size_t)(tm + row) * KC + ((c ^ (row & 7)) << 3);
    srcB[l] = BT + (size_t)(tn + row) * KC + ((c ^ (row & 7)) << 3);
    ldsOff[l] = g << 4;
  }

#define STAGE(sa, sb, kt) do { const int _k0 = (kt) << 6;                      \
    _Pragma("unroll") for (int _l = 0; _l < 4; ++_l) {                         \
      gload16(srcA[_l] + _k0, (char*)(sa) + ldsOff[_l]);                       \
      gload16(srcB[_l] + _k0, (char*)(sb) + ldsOff[_l]); } } while (0)

  const int swz = (lane & 7) << 4;
  const int r16 = lane & 15;
  const int kb = (lane >> 4) << 4;
#define LDA_(sa, fm, ks) (*(const bf16x8*)((const char*)(sa) + \
    (wm * 128 + (fm) * 16 + r16) * 128 + ((((ks) << 6) | kb) ^ swz)))
#define LDB_(sb, fn, ks) (*(const bf16x8*)((const char*)(sb) + \
    (wn * 64 + (fn) * 16 + r16) * 128 + ((((ks) << 6) | kb) ^ swz)))

  f32x4 acc[8][4];
#pragma unroll
  for (int i = 0; i < 8; ++i)
#pragma unroll
    for (int j = 0; j < 4; ++j) acc[i][j] = (f32x4){0.f, 0.f, 0.f, 0.f};

#define MM(i, j, a_, b_) acc[i][j] = __builtin_amdgcn_mfma_f32_16x16x32_bf16(a_, b_, acc[i][j], 0, 0, 0)

#define KTILE(sa, sb, ...) do {                                                \
  bf16x8 ka[4][2], kb0[2][2], kb1[2][2];                                       \
  _Pragma("unroll") for (int fm = 0; fm < 4; ++fm) {                           \
    ka[fm][0] = LDA_(sa, fm, 0); ka[fm][1] = LDA_(sa, fm, 1); }                \
  _Pragma("unroll") for (int fn = 0; fn < 2; ++fn) {                           \
    kb0[fn][0] = LDB_(sb, fn, 0); kb0[fn][1] = LDB_(sb, fn, 1); }              \
  __builtin_amdgcn_s_barrier();                                                \
  __builtin_amdgcn_s_setprio(1);                                               \
  _Pragma("unroll") for (int fm = 0; fm < 4; ++fm)                             \
    _Pragma("unroll") for (int fn = 0; fn < 2; ++fn) {                         \
      MM(fm, fn, ka[fm][0], kb0[fn][0]); MM(fm, fn, ka[fm][1], kb0[fn][1]); }  \
  __builtin_amdgcn_s_setprio(0);                                               \
  __builtin_amdgcn_s_barrier();                                                \
  _Pragma("unroll") for (int fn = 0; fn < 2; ++fn) {                           \
    kb1[fn][0] = LDB_(sb, 2 + fn, 0); kb1[fn][1] = LDB_(sb, 2 + fn, 1); }      \
  __builtin_amdgcn_s_barrier();                                                \
  __builtin_amdgcn_s_setprio(1);                                               \
  _Pragma("unroll") for (int fm = 0; fm < 4; ++fm)                             \
    _Pragma("unroll") for (int fn = 0; fn < 2; ++fn) {                         \
      MM(fm, 2 + fn, ka[fm][0], kb1[fn][0]); MM(fm, 2 + fn, ka[fm][1], kb1[fn][1]); } \
  __builtin_amdgcn_s_setprio(0);                                               \
  __builtin_amdgcn_s_barrier();                                                \
  _Pragma("unroll") for (int fm = 0; fm < 4; ++fm) {                           \
    ka[fm][0] = LDA_(sa, 4 + fm, 0); ka[fm][1] = LDA_(sa, 4 + fm, 1); }        \
  __builtin_amdgcn_s_barrier();                                                \
  __builtin_amdgcn_s_setprio(1);                                               \
  _Pragma("unroll") for (int fm = 0; fm < 4; ++fm)                             \
    _Pragma("unroll") for (int fn = 0; fn < 2; ++fn) {                         \
      MM(4 + fm, 2 + fn, ka[fm][0], kb1[fn][0]); MM(4 + fm, 2 + fn, ka[fm][1], kb1[fn][1]); } \
  __builtin_amdgcn_s_setprio(0);                                               \
  __builtin_amdgcn_s_barrier();                                                \
  __builtin_amdgcn_sched_barrier(0);                                           \
  __VA_ARGS__;                                                                 \
  __builtin_amdgcn_s_setprio(1);                                               \
  _Pragma("unroll") for (int fm = 0; fm < 4; ++fm)                             \
    _Pragma("unroll") for (int fn = 0; fn < 2; ++fn) {                         \
      MM(4 + fm, fn, ka[fm][0], kb0[fn][0]); MM(4 + fm, fn, ka[fm][1], kb0[fn][1]); } \
  __builtin_amdgcn_s_setprio(0);                                               \
} while (0)

#define TILE_ENTRY(vm) do { __builtin_amdgcn_sched_barrier(0);                 \
    asm volatile("s_waitcnt vmcnt(" #vm ")");                                  \
    __builtin_amdgcn_sched_barrier(0);                                         \
    __builtin_amdgcn_s_barrier();                                              \
    __builtin_amdgcn_sched_barrier(0); } while (0)

  STAGE(sA0, sB0, 0);
  STAGE(sA1, sB1, 1);

#pragma unroll 1
  for (int i = 0; i < 7; ++i) {
    TILE_ENTRY(8);
    KTILE(sA0, sB0, STAGE(sA0, sB0, 2 * i + 2));
    TILE_ENTRY(8);
    KTILE(sA1, sB1, STAGE(sA1, sB1, 2 * i + 3));
  }
  TILE_ENTRY(8);
  KTILE(sA0, sB0, (void)0);
  TILE_ENTRY(0);
  KTILE(sA1, sB1, (void)0);

  __syncthreads();

  // ---- blocked path: per-token sum-of-squares partials (q/k parts) ----
  const int part = tn >> 10;                  // 0=q 1=k 2=v
  const int cp = tn & 1023;
  const int bg = tm >> 8;
  const int hh = (cp >> 6) + wn;
  if constexpr (sizeof(OUT) == 2) {
    if (part < 2) {
#pragma unroll
      for (int fm = 0; fm < 8; ++fm)
#pragma unroll
        for (int r = 0; r < 4; ++r) {
          float s = acc[fm][0][r] * acc[fm][0][r] + acc[fm][1][r] * acc[fm][1][r]
                  + acc[fm][2][r] * acc[fm][2][r] + acc[fm][3][r] * acc[fm][3][r];
          s += __shfl_xor(s, 1, 64); s += __shfl_xor(s, 2, 64);
          s += __shfl_xor(s, 4, 64); s += __shfl_xor(s, 8, 64);
          if (r16 == 0) ssred[wn][wm * 128 + fm * 16 + (lane >> 4) * 4 + r] = s;
        }
      __syncthreads();
      if (tid < 256) {
        float s = ssred[0][tid] + ssred[1][tid] + ssred[2][tid] + ssred[3][tid];
        (part == 0 ? ssq : ssk)[(size_t)(tm + tid) * 4 + (cp >> 8)] = s;
      }
    }
  }

  // ---- epilogue: per-wave LDS repack -> coalesced wide stores ----
  u16* eb = (w == 0) ? sA0 : (w == 1) ? sA0 + 8192 : (w == 2) ? sA1 : (w == 3) ? sA1 + 8192
          : (w == 4) ? sB0 : (w == 5) ? sB0 + 8192 : (w == 6) ? sB1 : sB1 + 8192;
  float* fb = (float*)eb;                     // 16 x 68 f32 region per wave
  const int erow = lane >> 2, eseg = lane & 3;
  OUT* dstb;
  if constexpr (sizeof(OUT) == 2)
    dstb = C + (size_t)part * ((size_t)M_ * C_) + ((size_t)(bg * 16 + hh) * 256) * 64;
  else
    dstb = C + (size_t)(tm) * N + tn + wn * 64;
#pragma unroll
  for (int fm = 0; fm < 8; ++fm) {
#pragma unroll
    for (int fn = 0; fn < 4; ++fn)
#pragma unroll
      for (int r = 0; r < 4; ++r)
        fb[((lane >> 4) * 4 + r) * 68 + fn * 16 + (lane & 15)] = acc[fm][fn][r];
    asm volatile("s_waitcnt lgkmcnt(0)" ::: "memory");
    const float* src = &fb[erow * 68 + eseg * 16];
    f32x4 v0 = ((const f32x4*)src)[0], v1 = ((const f32x4*)src)[1];
    f32x4 v2 = ((const f32x4*)src)[2], v3 = ((const f32x4*)src)[3];
    OUT* dst;
    if constexpr (sizeof(OUT) == 2)
      dst = dstb + (size_t)(wm * 128 + fm * 16 + erow) * 64 + eseg * 16;
    else
      dst = dstb + (size_t)(wm * 128 + fm * 16 + erow) * N + eseg * 16;
    store16(dst, v0, v1, v2, v3);
  }
#undef STAGE
#undef LDA_
#undef LDB_
#undef MM
#undef KTILE
#undef TILE_ENTRY
}

// ---------------- block-causal attention ----------------
// grid 1024 = (bg, h). 256 thr (4 waves). Q/K read straight from global
// (head-blocked, L1/L2-resident). V scatter-transposed in LDS. P per-wave LDS.
// RMS scales from fp32 partials; lnw^2 folded into Q; kscl applied post-MFMA.
__global__ __launch_bounds__(256, 2) void attn_kernel(const u16* __restrict__ qkvblk,
                                                      const float* __restrict__ ssq,
                                                      const float* __restrict__ ssk,
                                                      const float* __restrict__ lnw,
                                                      u16* __restrict__ y) {
  const int bid = blockIdx.x;
  const int h = bid & 15;
  const int bg = bid >> 4;
  const size_t rowbase = (size_t)bg * 256;
  const u16* Qb = qkvblk + ((size_t)(bg * 16 + h) * 256) * 64;
  const u16* Kb = Qb + (size_t)M_ * C_;
  const u16* Vb = Qb + 2 * (size_t)M_ * C_;

  __shared__ __align__(16) u16 Vt[64 * 256];       // [hd][k_tok], XOR-swizzled
  __shared__ __align__(16) u16 Ps[4][16 * 256];    // per-wave P [q][k], XOR-swizzled
  __shared__ float kscl[256];

  const int tid = threadIdx.x;
  const int lane = tid & 63;
  const int w = tid >> 6;
  const int g = lane >> 4;
  const int qi = lane & 15;

  // stage V (scatter-transpose) + per-token k scales
  {
    const int r = tid;
    const u16* vr = Vb + (size_t)r * 64;
#pragma unroll
    for (int j = 0; j < 8; ++j) {
      bf16x8 vv = *(const bf16x8*)(vr + j * 8);
#pragma unroll
      for (int e = 0; e < 8; ++e) {
        int d = j * 8 + e;
        *(u16*)((char*)Vt + d * 512 + ((2 * r) ^ ((d & 7) << 4))) = (u16)vv[e];
      }
    }
    f32x4 kp = ((const f32x4*)ssk)[rowbase + r];
    kscl[r] = rsqrtf((kp[0] + kp[1] + kp[2] + kp[3]) * (1.0f / 1024.0f) + 1e-6f);
  }
  // per-lane lnw^2 factors for Q fragment columns
  float lnq0[8], lnq1[8];
#pragma unroll
  for (int e = 0; e < 8; ++e) {
    float a = lnw[h * 64 + g * 8 + e];
    float b = lnw[h * 64 + 32 + g * 8 + e];
    lnq0[e] = a * a; lnq1[e] = b * b;
  }
  __syncthreads();

  char* pb = (char*)Ps[w];
  const int swq = (qi & 7) << 4;

#pragma unroll 1
  for (int j = 0; j < 4; ++j) {
    // balanced tile set: {w, 7-w, 8+w, 15-w}
    const int qt = ((j >> 1) << 3) + ((j & 1) ? (7 - w) : w);
    const int q = qt * 16 + qi;

    f32x4 qv = ((const f32x4*)ssq)[rowbase + q];
    const float qsc = rsqrtf((qv[0] + qv[1] + qv[2] + qv[3]) * (1.0f / 1024.0f) + 1e-6f);
    const u16* qrow = Qb + (size_t)q * 64 + g * 8;
    bf16x8 q0 = *(const bf16x8*)(qrow);
    bf16x8 q1 = *(const bf16x8*)(qrow + 32);
#pragma unroll
    for (int e = 0; e < 8; ++e) {
      q0[e] = (short)f2bf(bf2f((u16)q0[e]) * qsc * lnq0[e]);
      q1[e] = (short)f2bf(bf2f((u16)q1[e]) * qsc * lnq1[e]);
    }

    f32x4 s[16];
#pragma unroll
    for (int n = 0; n < 16; ++n) {
      if (n <= qt) {
        const u16* krow = Kb + (size_t)(n * 16 + qi) * 64 + g * 8;
        bf16x8 ka0 = *(const bf16x8*)(krow);
        bf16x8 ka1 = *(const bf16x8*)(krow + 32);
        f32x4 a = {0.f, 0.f, 0.f, 0.f};
        a = __builtin_amdgcn_mfma_f32_16x16x32_bf16(ka0, q0, a, 0, 0, 0);
        a = __builtin_amdgcn_mfma_f32_16x16x32_bf16(ka1, q1, a, 0, 0, 0);
        s[n] = a;
      }
    }

    float m = -3e38f;
#pragma unroll
    for (int n = 0; n < 16; ++n) if (n <= qt) {
      f32x4 k4 = *(const f32x4*)&kscl[n * 16 + g * 4];
#pragma unroll
      for (int r = 0; r < 4; ++r) {
        const int k_abs = n * 16 + g * 4 + r;
        float v = s[n][r] * 0.125f * k4[r];
        v = (k_abs <= q) ? v : -3e38f;
        s[n][r] = v;
        m = fmaxf(m, v);
      }
    }
    m = fmaxf(m, __shfl_xor(m, 16, 64));
    m = fmaxf(m, __shfl_xor(m, 32, 64));

    float sum = 0.f;
#pragma unroll
    for (int n = 0; n < 16; ++n) if (n <= qt) {
#pragma unroll
      for (int r = 0; r < 4; ++r) {
        float p = __expf(s[n][r] - m);
        s[n][r] = p;
        sum += p;
      }
    }
    sum += __shfl_xor(sum, 16, 64);
    sum += __shfl_xor(sum, 32, 64);

#pragma unroll
    for (int n = 0; n < 16; ++n) if (n <= qt) {
      u16x4 pk = { f2bf(s[n][0]), f2bf(s[n][1]), f2bf(s[n][2]), f2bf(s[n][3]) };
      *(u16x4*)(pb + qi * 512 + ((n * 32 + g * 8) ^ swq)) = pk;
    }
    if (!(qt & 1)) {   // zero-pad k-tile qt+1 (read by the last 32-wide mfma)
      u16x4 z = {0, 0, 0, 0};
      *(u16x4*)(pb + qi * 512 + (((qt + 1) * 32 + g * 8) ^ swq)) = z;
    }

    f32x4 yacc[4];
#pragma unroll
    for (int dn = 0; dn < 4; ++dn) yacc[dn] = (f32x4){0.f, 0.f, 0.f, 0.f};
    const int nkf = qt / 2 + 1;
#pragma unroll
    for (int kf = 0; kf < 8; ++kf) if (kf < nkf) {
      bf16x8 pa = *(const bf16x8*)(pb + qi * 512 + ((kf * 64 + g * 16) ^ swq));
#pragma unroll
      for (int dn = 0; dn < 4; ++dn) {
        const int d = dn * 16 + qi;
        bf16x8 vb = *(const bf16x8*)((const char*)Vt + d * 512 + ((kf * 64 + g * 16) ^ swq));
        yacc[dn] = __builtin_amdgcn_mfma_f32_16x16x32_bf16(pa, vb, yacc[dn], 0, 0, 0);
      }
    }

#pragma unroll
    for (int r = 0; r < 4; ++r) {
      const float inv = 1.0f / __shfl(sum, g * 4 + r, 64);
      const size_t trow = rowbase + (size_t)qt * 16 + g * 4 + r;
      u16* yrow = y + trow * C_ + h * 64 + qi;
#pragma unroll
      for (int dn = 0; dn < 4; ++dn) yrow[dn * 16] = f2bf(yacc[dn][r] * inv);
    }
  }
}

// ---------------- launch ----------------
extern "C" void kernel_launch(void* const* d_in, const int* in_sizes, int n_in,
                              void* d_out, int out_size, void* d_ws, size_t ws_size,
                              hipStream_t stream) {
  const float* x      = (const float*)d_in[0];   // [16384][1024]
  const float* w_qkv  = (const float*)d_in[1];   // [1024][3072]
  const float* ln_w   = (const float*)d_in[2];   // [1024]
  const float* w_proj = (const float*)d_in[3];   // [1024][1024]
  float* out = (float*)d_out;                    // [16384][1024] fp32

  u16* xb     = (u16*)d_ws;                          // 16384*1024
  u16* wqkvT  = xb + (size_t)M_ * C_;                // 3072*1024 (transposed)
  u16* wprojT = wqkvT + (size_t)N1_ * C_;            // 1024*1024 (transposed)
  u16* qkvblk = wprojT + (size_t)C_ * C_;            // 3 * 16384*1024 head-blocked
  u16* yb     = qkvblk + 3 * (size_t)M_ * C_;        // 16384*1024
  float* ssq  = (float*)(yb + (size_t)M_ * C_);      // 16384*4 f32
  float* ssk  = ssq + (size_t)M_ * 4;                // 16384*4 f32

  cast_f32_bf16<<<(M_ * C_) / 1024, 256, 0, stream>>>(x, xb);
  transpose_cast<<<dim3(N1_ / 64, C_ / 64), 256, 0, stream>>>(w_qkv, wqkvT, C_, N1_);
  transpose_cast<<<dim3(C_ / 64, C_ / 64), 256, 0, stream>>>(w_proj, wprojT, C_, C_);

  gemm256<u16><<<(M_ / 256) * (N1_ / 256), 512, 0, stream>>>(xb, wqkvT, qkvblk, M_, N1_, N1_ / 256, ssq, ssk);
  attn_kernel<<<64 * 16, 256, 0, stream>>>(qkvblk, ssq, ssk, ln_w, yb);
  gemm256<float><<<(M_ / 256) * (C_ / 256), 512, 0, stream>>>(yb, wprojT, out, M_, C_, C_ / 256, nullptr, nullptr);
}